// Round 1
// baseline (370.076 us; speedup 1.0000x reference)
//
#include <hip/hip_runtime.h>
#include <hip/hip_bf16.h>
#include <math.h>

typedef __bf16 bf16x8 __attribute__((ext_vector_type(8)));
typedef unsigned short u16x8 __attribute__((ext_vector_type(8)));
typedef float f32x4 __attribute__((ext_vector_type(4)));

#define T_TOK 2048
#define HD 1024
#define ID 768
#define NE 16
#define NEZ 24
#define NK 4
#define SCALE_F 2.5f

__device__ __forceinline__ unsigned short f2bf(float f) {
  unsigned int u = __builtin_bit_cast(unsigned int, f);
  u += 0x7FFFu + ((u >> 16) & 1u);          // RNE
  return (unsigned short)(u >> 16);
}

__device__ __forceinline__ bf16x8 ld_cvt8(const float* __restrict__ p) {
  float4 a = *reinterpret_cast<const float4*>(p);
  float4 b = *reinterpret_cast<const float4*>(p + 4);
  u16x8 t;
  t[0] = f2bf(a.x); t[1] = f2bf(a.y); t[2] = f2bf(a.z); t[3] = f2bf(a.w);
  t[4] = f2bf(b.x); t[5] = f2bf(b.y); t[6] = f2bf(b.z); t[7] = f2bf(b.w);
  return __builtin_bit_cast(bf16x8, t);
}

// ---------------- router: logits -> sigmoid -> top4(+bias) -> cw/zero_w ----
__global__ __launch_bounds__(64) void router_k(
    const float* __restrict__ x, const float* __restrict__ wr,
    const float* __restrict__ bias,
    float* __restrict__ cw, float* __restrict__ zero_w,
    unsigned short* __restrict__ xb, float* __restrict__ out) {
  const int t = blockIdx.x;
  __shared__ float xs[HD];
  __shared__ float sc[NEZ], scb[NEZ];
  __shared__ float zw_s;
  const int l = threadIdx.x;
  for (int i = l; i < HD; i += 64) {
    float v = x[(size_t)t * HD + i];
    xs[i] = v;
    xb[(size_t)t * HD + i] = f2bf(v);
  }
  __syncthreads();
  if (l < NEZ) {
    const float* w = wr + (size_t)l * HD;
    float a0 = 0.f, a1 = 0.f, a2 = 0.f, a3 = 0.f;
    for (int h = 0; h < HD; h += 4) {
      a0 = fmaf(xs[h + 0], w[h + 0], a0);
      a1 = fmaf(xs[h + 1], w[h + 1], a1);
      a2 = fmaf(xs[h + 2], w[h + 2], a2);
      a3 = fmaf(xs[h + 3], w[h + 3], a3);
    }
    float lg = (a0 + a1) + (a2 + a3);
    float s = 1.0f / (1.0f + expf(-lg));
    sc[l] = s;
    scb[l] = s + bias[l];
  }
  __syncthreads();
  if (l == 0) {
    float cwl[NE];
    for (int e = 0; e < NE; ++e) cwl[e] = 0.f;
    unsigned picked = 0;
    int ids[NK]; float wv[NK]; float ssum = 0.f;
    for (int k = 0; k < NK; ++k) {
      int best = -1; float bv = -1e30f;
      for (int e = 0; e < NEZ; ++e) {
        if ((picked >> e) & 1u) continue;
        if (scb[e] > bv) { bv = scb[e]; best = e; }
      }
      picked |= 1u << best;
      ids[k] = best; wv[k] = sc[best]; ssum += sc[best];
    }
    float zw = 0.f;
    for (int k = 0; k < NK; ++k) {
      float w = wv[k] / ssum * SCALE_F;
      if (ids[k] >= NE) zw += w; else cwl[ids[k]] += w;
    }
    for (int e = 0; e < NE; ++e) cw[(size_t)t * NE + e] = cwl[e];
    zero_w[t] = zw;
    zw_s = zw;
  }
  __syncthreads();
  const float zw = zw_s;
  for (int i = l; i < HD; i += 64) out[(size_t)t * HD + i] = xs[i] * zw;
}

// ---------------- build per-expert token lists -----------------------------
__global__ void build_k(const float* __restrict__ cw, int* __restrict__ counts,
                        int* __restrict__ lists, float* __restrict__ wlist) {
  int t = blockIdx.x * blockDim.x + threadIdx.x;
  if (t >= T_TOK) return;
  for (int e = 0; e < NE; ++e) {
    float w = cw[(size_t)t * NE + e];
    if (w != 0.f) {
      int p = atomicAdd(&counts[e], 1);
      lists[e * T_TOK + p] = t;
      wlist[e * T_TOK + p] = w;
    }
  }
}

__global__ void scan_k(const int* __restrict__ counts, int* __restrict__ offs) {
  if (threadIdx.x == 0 && blockIdx.x == 0) {
    int s = 0;
    for (int e = 0; e < NE; ++e) { offs[e] = s; s += counts[e]; }
    offs[NE] = s;
  }
}

// ---------------- grouped gate/up GEMM + silu*u -> abuf (bf16) -------------
// block: 256 thr = 4 waves; tile 128(M) x 64(N); wave = 64x32 (4x2 frags)
__global__ __launch_bounds__(256, 2) void gu_k(
    const unsigned short* __restrict__ xb,
    const float* __restrict__ wg, const float* __restrict__ wu,
    const int* __restrict__ counts, const int* __restrict__ offs,
    const int* __restrict__ lists, unsigned short* __restrict__ abuf) {
  const int e = blockIdx.z;
  const int cnt = counts[e];
  const int m0 = blockIdx.y * 128;
  if (m0 >= cnt) return;
  const int n0 = blockIdx.x * 64;
  __shared__ int toks[128];
  const int tid = threadIdx.x;
  if (tid < 128) {
    int m = m0 + tid;
    toks[tid] = (m < cnt) ? lists[e * T_TOK + m] : 0;
  }
  __syncthreads();
  const int wid = tid >> 6, l = tid & 63;
  const int wm = (wid >> 1) * 64, wn = (wid & 1) * 32;
  const int q = l >> 4, r = l & 15;
  const unsigned short* ap[4];
#pragma unroll
  for (int fm = 0; fm < 4; ++fm)
    ap[fm] = xb + (size_t)toks[wm + fm * 16 + r] * HD + q * 8;
  const size_t wbase = (size_t)e * ID * HD;
  const float* bgp[2]; const float* bup[2];
#pragma unroll
  for (int fn = 0; fn < 2; ++fn) {
    int col = n0 + wn + fn * 16 + r;
    bgp[fn] = wg + wbase + (size_t)col * HD + q * 8;
    bup[fn] = wu + wbase + (size_t)col * HD + q * 8;
  }
  f32x4 ag[4][2] = {}; f32x4 au[4][2] = {};
  for (int k0 = 0; k0 < HD; k0 += 32) {
    bf16x8 a[4];
#pragma unroll
    for (int fm = 0; fm < 4; ++fm)
      a[fm] = *reinterpret_cast<const bf16x8*>(ap[fm] + k0);
    bf16x8 bg[2], bu[2];
#pragma unroll
    for (int fn = 0; fn < 2; ++fn) {
      bg[fn] = ld_cvt8(bgp[fn] + k0);
      bu[fn] = ld_cvt8(bup[fn] + k0);
    }
#pragma unroll
    for (int fm = 0; fm < 4; ++fm)
#pragma unroll
      for (int fn = 0; fn < 2; ++fn) {
        ag[fm][fn] = __builtin_amdgcn_mfma_f32_16x16x32_bf16(a[fm], bg[fn], ag[fm][fn], 0, 0, 0);
        au[fm][fn] = __builtin_amdgcn_mfma_f32_16x16x32_bf16(a[fm], bu[fn], au[fm][fn], 0, 0, 0);
      }
  }
  const int rowbase = offs[e] + m0;
#pragma unroll
  for (int fm = 0; fm < 4; ++fm)
#pragma unroll
    for (int fn = 0; fn < 2; ++fn)
#pragma unroll
      for (int i2 = 0; i2 < 4; ++i2) {
        int mr = wm + fm * 16 + q * 4 + i2;       // D: row=(l>>4)*4+reg
        if (m0 + mr < cnt) {
          float g = ag[fm][fn][i2], u = au[fm][fn][i2];
          float s = 1.0f / (1.0f + expf(-g));
          float aa = g * s * u;                   // silu(g)*u
          int col = n0 + wn + fn * 16 + r;        // D: col=l&15
          abuf[(size_t)(rowbase + mr) * ID + col] = f2bf(aa);
        }
      }
}

// ---------------- grouped down GEMM, weighted atomic combine ---------------
__global__ __launch_bounds__(256, 2) void dn_k(
    const unsigned short* __restrict__ abuf,
    const float* __restrict__ wd,
    const int* __restrict__ counts, const int* __restrict__ offs,
    const int* __restrict__ lists, const float* __restrict__ wlist,
    float* __restrict__ out) {
  const int e = blockIdx.z;
  const int cnt = counts[e];
  const int m0 = blockIdx.y * 128;
  if (m0 >= cnt) return;
  const int n0 = blockIdx.x * 64;
  __shared__ int toks[128];
  __shared__ float wts[128];
  const int tid = threadIdx.x;
  if (tid < 128) {
    int m = m0 + tid;
    if (m < cnt) { toks[tid] = lists[e * T_TOK + m]; wts[tid] = wlist[e * T_TOK + m]; }
    else         { toks[tid] = 0;                    wts[tid] = 0.f; }
  }
  __syncthreads();
  const int wid = tid >> 6, l = tid & 63;
  const int wm = (wid >> 1) * 64, wn = (wid & 1) * 32;
  const int q = l >> 4, r = l & 15;
  const int rowbase = offs[e] + m0;
  const unsigned short* ap[4];
#pragma unroll
  for (int fm = 0; fm < 4; ++fm) {
    int mr = wm + fm * 16 + r;
    int row = (m0 + mr < cnt) ? (rowbase + mr) : rowbase;
    ap[fm] = abuf + (size_t)row * ID + q * 8;
  }
  const float* bp[2];
#pragma unroll
  for (int fn = 0; fn < 2; ++fn) {
    int col = n0 + wn + fn * 16 + r;
    bp[fn] = wd + (size_t)e * HD * ID + (size_t)col * ID + q * 8;
  }
  f32x4 acc[4][2] = {};
  for (int k0 = 0; k0 < ID; k0 += 32) {
    bf16x8 a[4];
#pragma unroll
    for (int fm = 0; fm < 4; ++fm)
      a[fm] = *reinterpret_cast<const bf16x8*>(ap[fm] + k0);
    bf16x8 b[2];
#pragma unroll
    for (int fn = 0; fn < 2; ++fn) b[fn] = ld_cvt8(bp[fn] + k0);
#pragma unroll
    for (int fm = 0; fm < 4; ++fm)
#pragma unroll
      for (int fn = 0; fn < 2; ++fn)
        acc[fm][fn] = __builtin_amdgcn_mfma_f32_16x16x32_bf16(a[fm], b[fn], acc[fm][fn], 0, 0, 0);
  }
#pragma unroll
  for (int fm = 0; fm < 4; ++fm)
#pragma unroll
    for (int fn = 0; fn < 2; ++fn)
#pragma unroll
      for (int i2 = 0; i2 < 4; ++i2) {
        int mr = wm + fm * 16 + q * 4 + i2;
        if (m0 + mr < cnt) {
          int col = n0 + wn + fn * 16 + r;
          atomicAdd(&out[(size_t)toks[mr] * HD + col], acc[fm][fn][i2] * wts[mr]);
        }
      }
}

extern "C" void kernel_launch(void* const* d_in, const int* in_sizes, int n_in,
                              void* d_out, int out_size, void* d_ws, size_t ws_size,
                              hipStream_t stream) {
  (void)in_sizes; (void)n_in; (void)out_size; (void)ws_size;
  const float* x    = (const float*)d_in[0];
  const float* wr   = (const float*)d_in[3];
  const float* bias = (const float*)d_in[4];
  const float* wg   = (const float*)d_in[5];
  const float* wu   = (const float*)d_in[6];
  const float* wd   = (const float*)d_in[7];
  float* out = (float*)d_out;

  char* p = (char*)d_ws;
  auto alloc = [&](size_t bytes) {
    char* r = p;
    p += (bytes + 255) & ~(size_t)255;
    return r;
  };
  float* cw      = (float*)alloc((size_t)T_TOK * NE * 4);
  float* zero_w  = (float*)alloc((size_t)T_TOK * 4);
  int*   counts  = (int*)alloc(NE * 4);
  int*   offs    = (int*)alloc((NE + 1) * 4);
  int*   lists   = (int*)alloc((size_t)NE * T_TOK * 4);
  float* wlist   = (float*)alloc((size_t)NE * T_TOK * 4);
  unsigned short* xb   = (unsigned short*)alloc((size_t)T_TOK * HD * 2);
  unsigned short* abuf = (unsigned short*)alloc((size_t)T_TOK * NK * ID * 2);
  (void)zero_w;

  hipMemsetAsync(counts, 0, NE * 4, stream);
  router_k<<<T_TOK, 64, 0, stream>>>(x, wr, bias, cw, zero_w, xb, out);
  build_k<<<T_TOK / 256, 256, 0, stream>>>(cw, counts, lists, wlist);
  scan_k<<<1, 64, 0, stream>>>(counts, offs);
  gu_k<<<dim3(ID / 64, T_TOK / 128, NE), 256, 0, stream>>>(xb, wg, wu, counts, offs, lists, abuf);
  dn_k<<<dim3(HD / 64, T_TOK / 128, NE), 256, 0, stream>>>(abuf, wd, counts, offs, lists, wlist, out);
}

// Round 2
// 340.560 us; speedup vs baseline: 1.0867x; 1.0867x over previous
//
#include <hip/hip_runtime.h>
#include <hip/hip_bf16.h>
#include <math.h>

typedef __bf16 bf16x8 __attribute__((ext_vector_type(8)));
typedef unsigned short u16x8 __attribute__((ext_vector_type(8)));
typedef float f32x4 __attribute__((ext_vector_type(4)));

#define T_TOK 2048
#define HD 1024
#define ID 768
#define NE 16
#define NEZ 24
#define NK 4
#define SCALE_F 2.5f

__device__ __forceinline__ unsigned short f2bf(float f) {
  unsigned int u = __builtin_bit_cast(unsigned int, f);
  u += 0x7FFFu + ((u >> 16) & 1u);          // RNE
  return (unsigned short)(u >> 16);
}

// native casts -> compiler emits v_cvt_pk_bf16_f32 (RNE)
__device__ __forceinline__ bf16x8 cvt8(float4 a, float4 b) {
  bf16x8 t;
  t[0] = (__bf16)a.x; t[1] = (__bf16)a.y; t[2] = (__bf16)a.z; t[3] = (__bf16)a.w;
  t[4] = (__bf16)b.x; t[5] = (__bf16)b.y; t[6] = (__bf16)b.z; t[7] = (__bf16)b.w;
  return t;
}

// ---------------- router: logits -> sigmoid -> top4(+bias) -> cw/zero_w ----
__global__ __launch_bounds__(64) void router_k(
    const float* __restrict__ x, const float* __restrict__ wr,
    const float* __restrict__ bias,
    float* __restrict__ cw, float* __restrict__ zero_w,
    unsigned short* __restrict__ xb, float* __restrict__ out) {
  const int t = blockIdx.x;
  __shared__ float xs[HD];
  __shared__ float sc[NEZ], scb[NEZ];
  __shared__ float zw_s;
  const int l = threadIdx.x;
  for (int i = l; i < HD; i += 64) {
    float v = x[(size_t)t * HD + i];
    xs[i] = v;
    xb[(size_t)t * HD + i] = f2bf(v);
  }
  __syncthreads();
  if (l < NEZ) {
    const float* w = wr + (size_t)l * HD;
    float a0 = 0.f, a1 = 0.f, a2 = 0.f, a3 = 0.f;
    for (int h = 0; h < HD; h += 4) {
      a0 = fmaf(xs[h + 0], w[h + 0], a0);
      a1 = fmaf(xs[h + 1], w[h + 1], a1);
      a2 = fmaf(xs[h + 2], w[h + 2], a2);
      a3 = fmaf(xs[h + 3], w[h + 3], a3);
    }
    float lg = (a0 + a1) + (a2 + a3);
    float s = 1.0f / (1.0f + expf(-lg));
    sc[l] = s;
    scb[l] = s + bias[l];
  }
  __syncthreads();
  if (l == 0) {
    float cwl[NE];
    for (int e = 0; e < NE; ++e) cwl[e] = 0.f;
    unsigned picked = 0;
    int ids[NK]; float wv[NK]; float ssum = 0.f;
    for (int k = 0; k < NK; ++k) {
      int best = -1; float bv = -1e30f;
      for (int e = 0; e < NEZ; ++e) {
        if ((picked >> e) & 1u) continue;
        if (scb[e] > bv) { bv = scb[e]; best = e; }
      }
      picked |= 1u << best;
      ids[k] = best; wv[k] = sc[best]; ssum += sc[best];
    }
    float zw = 0.f;
    for (int k = 0; k < NK; ++k) {
      float w = wv[k] / ssum * SCALE_F;
      if (ids[k] >= NE) zw += w; else cwl[ids[k]] += w;
    }
    for (int e = 0; e < NE; ++e) cw[(size_t)t * NE + e] = cwl[e];
    zero_w[t] = zw;
    zw_s = zw;
  }
  __syncthreads();
  const float zw = zw_s;
  for (int i = l; i < HD; i += 64) out[(size_t)t * HD + i] = xs[i] * zw;
}

// ---------------- build per-expert token lists -----------------------------
__global__ void build_k(const float* __restrict__ cw, int* __restrict__ counts,
                        int* __restrict__ lists, float* __restrict__ wlist) {
  int t = blockIdx.x * blockDim.x + threadIdx.x;
  if (t >= T_TOK) return;
  for (int e = 0; e < NE; ++e) {
    float w = cw[(size_t)t * NE + e];
    if (w != 0.f) {
      int p = atomicAdd(&counts[e], 1);
      lists[e * T_TOK + p] = t;
      wlist[e * T_TOK + p] = w;
    }
  }
}

__global__ void scan_k(const int* __restrict__ counts, int* __restrict__ offs) {
  if (threadIdx.x == 0 && blockIdx.x == 0) {
    int s = 0;
    for (int e = 0; e < NE; ++e) { offs[e] = s; s += counts[e]; }
    offs[NE] = s;
  }
}

// ============================ gate/up GEMM =================================
// block: 256 thr = 4 waves; tile 128(M) x 64(N); wave = 64x32 (4x2 frags)
// depth-1 register pipeline: all loads of half-step i+1 issued before
// cvt+MFMA of half-step i (two named operand sets, unroll-2 rotation).

struct GuSet {
  bf16x8 a[4];
  float4 g[2][2];
  float4 u[2][2];
};

__device__ __forceinline__ void gu_load(GuSet& S,
    const unsigned short* const* ap, const float* const* bgp,
    const float* const* bup, int k) {
#pragma unroll
  for (int fm = 0; fm < 4; ++fm)
    S.a[fm] = *reinterpret_cast<const bf16x8*>(ap[fm] + k);
#pragma unroll
  for (int fn = 0; fn < 2; ++fn) {
    S.g[fn][0] = *reinterpret_cast<const float4*>(bgp[fn] + k);
    S.g[fn][1] = *reinterpret_cast<const float4*>(bgp[fn] + k + 4);
    S.u[fn][0] = *reinterpret_cast<const float4*>(bup[fn] + k);
    S.u[fn][1] = *reinterpret_cast<const float4*>(bup[fn] + k + 4);
  }
}

__device__ __forceinline__ void gu_comp(const GuSet& S,
    f32x4 (&ag)[4][2], f32x4 (&au)[4][2]) {
  bf16x8 bg[2], bu[2];
#pragma unroll
  for (int fn = 0; fn < 2; ++fn) {
    bg[fn] = cvt8(S.g[fn][0], S.g[fn][1]);
    bu[fn] = cvt8(S.u[fn][0], S.u[fn][1]);
  }
#pragma unroll
  for (int fm = 0; fm < 4; ++fm)
#pragma unroll
    for (int fn = 0; fn < 2; ++fn) {
      ag[fm][fn] = __builtin_amdgcn_mfma_f32_16x16x32_bf16(S.a[fm], bg[fn], ag[fm][fn], 0, 0, 0);
      au[fm][fn] = __builtin_amdgcn_mfma_f32_16x16x32_bf16(S.a[fm], bu[fn], au[fm][fn], 0, 0, 0);
    }
}

__global__ __launch_bounds__(256) void gu_k(
    const unsigned short* __restrict__ xb,
    const float* __restrict__ wg, const float* __restrict__ wu,
    const int* __restrict__ counts, const int* __restrict__ offs,
    const int* __restrict__ lists, unsigned short* __restrict__ abuf) {
  const int e = blockIdx.z;
  const int cnt = counts[e];
  const int m0 = blockIdx.y * 128;
  if (m0 >= cnt) return;
  const int n0 = blockIdx.x * 64;
  __shared__ int toks[128];
  const int tid = threadIdx.x;
  if (tid < 128) {
    int m = m0 + tid;
    toks[tid] = (m < cnt) ? lists[e * T_TOK + m] : 0;
  }
  __syncthreads();
  const int wid = tid >> 6, l = tid & 63;
  const int wm = (wid >> 1) * 64, wn = (wid & 1) * 32;
  const int q = l >> 4, r = l & 15;
  const unsigned short* ap[4];
#pragma unroll
  for (int fm = 0; fm < 4; ++fm)
    ap[fm] = xb + (size_t)toks[wm + fm * 16 + r] * HD + q * 8;
  const size_t wbase = (size_t)e * ID * HD;
  const float* bgp[2]; const float* bup[2];
#pragma unroll
  for (int fn = 0; fn < 2; ++fn) {
    int col = n0 + wn + fn * 16 + r;
    bgp[fn] = wg + wbase + (size_t)col * HD + q * 8;
    bup[fn] = wu + wbase + (size_t)col * HD + q * 8;
  }
  f32x4 ag[4][2] = {}; f32x4 au[4][2] = {};

  GuSet S0, S1;
  gu_load(S0, ap, bgp, bup, 0);
  for (int k = 32; k < HD; k += 64) {
    gu_load(S1, ap, bgp, bup, k);
    gu_comp(S0, ag, au);
    gu_load(S0, ap, bgp, bup, (k + 32) & (HD - 1));  // last one wraps (dummy)
    gu_comp(S1, ag, au);
  }

  const int rowbase = offs[e] + m0;
#pragma unroll
  for (int fm = 0; fm < 4; ++fm)
#pragma unroll
    for (int fn = 0; fn < 2; ++fn)
#pragma unroll
      for (int i2 = 0; i2 < 4; ++i2) {
        int mr = wm + fm * 16 + q * 4 + i2;       // D: row=(l>>4)*4+reg
        if (m0 + mr < cnt) {
          float g = ag[fm][fn][i2], u = au[fm][fn][i2];
          float s = 1.0f / (1.0f + expf(-g));
          float aa = g * s * u;                   // silu(g)*u
          int col = n0 + wn + fn * 16 + r;        // D: col=l&15
          abuf[(size_t)(rowbase + mr) * ID + col] = f2bf(aa);
        }
      }
}

// ============================ down GEMM ====================================
struct DnSet {
  bf16x8 a[4];
  float4 b[2][2];
};

__device__ __forceinline__ void dn_load(DnSet& S,
    const unsigned short* const* ap, const float* const* bp, int k) {
#pragma unroll
  for (int fm = 0; fm < 4; ++fm)
    S.a[fm] = *reinterpret_cast<const bf16x8*>(ap[fm] + k);
#pragma unroll
  for (int fn = 0; fn < 2; ++fn) {
    S.b[fn][0] = *reinterpret_cast<const float4*>(bp[fn] + k);
    S.b[fn][1] = *reinterpret_cast<const float4*>(bp[fn] + k + 4);
  }
}

__device__ __forceinline__ void dn_comp(const DnSet& S, f32x4 (&acc)[4][2]) {
  bf16x8 b[2];
#pragma unroll
  for (int fn = 0; fn < 2; ++fn) b[fn] = cvt8(S.b[fn][0], S.b[fn][1]);
#pragma unroll
  for (int fm = 0; fm < 4; ++fm)
#pragma unroll
    for (int fn = 0; fn < 2; ++fn)
      acc[fm][fn] = __builtin_amdgcn_mfma_f32_16x16x32_bf16(S.a[fm], b[fn], acc[fm][fn], 0, 0, 0);
}

__global__ __launch_bounds__(256) void dn_k(
    const unsigned short* __restrict__ abuf,
    const float* __restrict__ wd,
    const int* __restrict__ counts, const int* __restrict__ offs,
    const int* __restrict__ lists, const float* __restrict__ wlist,
    float* __restrict__ out) {
  const int e = blockIdx.z;
  const int cnt = counts[e];
  const int m0 = blockIdx.y * 128;
  if (m0 >= cnt) return;
  const int n0 = blockIdx.x * 64;
  __shared__ int toks[128];
  __shared__ float wts[128];
  const int tid = threadIdx.x;
  if (tid < 128) {
    int m = m0 + tid;
    if (m < cnt) { toks[tid] = lists[e * T_TOK + m]; wts[tid] = wlist[e * T_TOK + m]; }
    else         { toks[tid] = 0;                    wts[tid] = 0.f; }
  }
  __syncthreads();
  const int wid = tid >> 6, l = tid & 63;
  const int wm = (wid >> 1) * 64, wn = (wid & 1) * 32;
  const int q = l >> 4, r = l & 15;
  const int rowbase = offs[e] + m0;
  const unsigned short* ap[4];
#pragma unroll
  for (int fm = 0; fm < 4; ++fm) {
    int mr = wm + fm * 16 + r;
    int row = (m0 + mr < cnt) ? (rowbase + mr) : rowbase;
    ap[fm] = abuf + (size_t)row * ID + q * 8;
  }
  const float* bp[2];
#pragma unroll
  for (int fn = 0; fn < 2; ++fn) {
    int col = n0 + wn + fn * 16 + r;
    bp[fn] = wd + (size_t)e * HD * ID + (size_t)col * ID + q * 8;
  }
  f32x4 acc[4][2] = {};

  DnSet S0, S1;
  dn_load(S0, ap, bp, 0);
  for (int k = 32; k < ID; k += 64) {
    dn_load(S1, ap, bp, k);
    dn_comp(S0, acc);
    int kn = k + 32; if (kn >= ID) kn = 0;        // last one wraps (dummy)
    dn_load(S0, ap, bp, kn);
    dn_comp(S1, acc);
  }

#pragma unroll
  for (int fm = 0; fm < 4; ++fm)
#pragma unroll
    for (int fn = 0; fn < 2; ++fn)
#pragma unroll
      for (int i2 = 0; i2 < 4; ++i2) {
        int mr = wm + fm * 16 + q * 4 + i2;
        if (m0 + mr < cnt) {
          int col = n0 + wn + fn * 16 + r;
          atomicAdd(&out[(size_t)toks[mr] * HD + col], acc[fm][fn][i2] * wts[mr]);
        }
      }
}

extern "C" void kernel_launch(void* const* d_in, const int* in_sizes, int n_in,
                              void* d_out, int out_size, void* d_ws, size_t ws_size,
                              hipStream_t stream) {
  (void)in_sizes; (void)n_in; (void)out_size; (void)ws_size;
  const float* x    = (const float*)d_in[0];
  const float* wr   = (const float*)d_in[3];
  const float* bias = (const float*)d_in[4];
  const float* wg   = (const float*)d_in[5];
  const float* wu   = (const float*)d_in[6];
  const float* wd   = (const float*)d_in[7];
  float* out = (float*)d_out;

  char* p = (char*)d_ws;
  auto alloc = [&](size_t bytes) {
    char* r = p;
    p += (bytes + 255) & ~(size_t)255;
    return r;
  };
  float* cw      = (float*)alloc((size_t)T_TOK * NE * 4);
  float* zero_w  = (float*)alloc((size_t)T_TOK * 4);
  int*   counts  = (int*)alloc(NE * 4);
  int*   offs    = (int*)alloc((NE + 1) * 4);
  int*   lists   = (int*)alloc((size_t)NE * T_TOK * 4);
  float* wlist   = (float*)alloc((size_t)NE * T_TOK * 4);
  unsigned short* xb   = (unsigned short*)alloc((size_t)T_TOK * HD * 2);
  unsigned short* abuf = (unsigned short*)alloc((size_t)T_TOK * NK * ID * 2);
  (void)zero_w;

  hipMemsetAsync(counts, 0, NE * 4, stream);
  router_k<<<T_TOK, 64, 0, stream>>>(x, wr, bias, cw, zero_w, xb, out);
  build_k<<<T_TOK / 256, 256, 0, stream>>>(cw, counts, lists, wlist);
  scan_k<<<1, 64, 0, stream>>>(counts, offs);
  gu_k<<<dim3(ID / 64, T_TOK / 128, NE), 256, 0, stream>>>(xb, wg, wu, counts, offs, lists, abuf);
  dn_k<<<dim3(HD / 64, T_TOK / 128, NE), 256, 0, stream>>>(abuf, wd, counts, offs, lists, wlist, out);
}

// Round 3
// 154.565 us; speedup vs baseline: 2.3943x; 2.2033x over previous
//
#include <hip/hip_runtime.h>
#include <hip/hip_bf16.h>
#include <math.h>

typedef __bf16 bf16x8 __attribute__((ext_vector_type(8)));
typedef float f32x4 __attribute__((ext_vector_type(4)));

#define T_TOK 2048
#define HD 1024
#define ID 768
#define NE 16
#define NEZ 24
#define NK 4
#define SCALE_F 2.5f

#define MFMA(a, b, c) __builtin_amdgcn_mfma_f32_16x16x32_bf16(a, b, c, 0, 0, 0)

__device__ __forceinline__ unsigned short f2bf(float f) {
  unsigned int u = __builtin_bit_cast(unsigned int, f);
  u += 0x7FFFu + ((u >> 16) & 1u);          // RNE
  return (unsigned short)(u >> 16);
}

// native casts -> v_cvt_pk_bf16_f32
__device__ __forceinline__ bf16x8 cvt8(float4 a, float4 b) {
  bf16x8 t;
  t[0] = (__bf16)a.x; t[1] = (__bf16)a.y; t[2] = (__bf16)a.z; t[3] = (__bf16)a.w;
  t[4] = (__bf16)b.x; t[5] = (__bf16)b.y; t[6] = (__bf16)b.z; t[7] = (__bf16)b.w;
  return t;
}

// async global->LDS, 16B per lane; dest must be linear (base + lane*16)
__device__ __forceinline__ void gload16(const void* g, void* l) {
  __builtin_amdgcn_global_load_lds(
      (const __attribute__((address_space(1))) void*)(unsigned long long)(uintptr_t)g,
      (__attribute__((address_space(3))) void*)(uintptr_t)l, 16, 0, 0);
}

// ---------------- router: logits -> sigmoid -> top4(+bias) -> cw/zero_w ----
__global__ __launch_bounds__(64) void router_k(
    const float* __restrict__ x, const float* __restrict__ wr,
    const float* __restrict__ bias,
    float* __restrict__ cw, float* __restrict__ zero_w,
    unsigned short* __restrict__ xb, float* __restrict__ out) {
  const int t = blockIdx.x;
  __shared__ float xs[HD];
  __shared__ float sc[NEZ], scb[NEZ];
  __shared__ float zw_s;
  const int l = threadIdx.x;
  for (int i = l; i < HD; i += 64) {
    float v = x[(size_t)t * HD + i];
    xs[i] = v;
    xb[(size_t)t * HD + i] = f2bf(v);
  }
  __syncthreads();
  if (l < NEZ) {
    const float* w = wr + (size_t)l * HD;
    float a0 = 0.f, a1 = 0.f, a2 = 0.f, a3 = 0.f;
    for (int h = 0; h < HD; h += 4) {
      a0 = fmaf(xs[h + 0], w[h + 0], a0);
      a1 = fmaf(xs[h + 1], w[h + 1], a1);
      a2 = fmaf(xs[h + 2], w[h + 2], a2);
      a3 = fmaf(xs[h + 3], w[h + 3], a3);
    }
    float lg = (a0 + a1) + (a2 + a3);
    float s = 1.0f / (1.0f + expf(-lg));
    sc[l] = s;
    scb[l] = s + bias[l];
  }
  __syncthreads();
  if (l == 0) {
    float cwl[NE];
    for (int e = 0; e < NE; ++e) cwl[e] = 0.f;
    unsigned picked = 0;
    int ids[NK]; float wv[NK]; float ssum = 0.f;
    for (int k = 0; k < NK; ++k) {
      int best = -1; float bv = -1e30f;
      for (int e = 0; e < NEZ; ++e) {
        if ((picked >> e) & 1u) continue;
        if (scb[e] > bv) { bv = scb[e]; best = e; }
      }
      picked |= 1u << best;
      ids[k] = best; wv[k] = sc[best]; ssum += sc[best];
    }
    float zw = 0.f;
    for (int k = 0; k < NK; ++k) {
      float w = wv[k] / ssum * SCALE_F;
      if (ids[k] >= NE) zw += w; else cwl[ids[k]] += w;
    }
    for (int e = 0; e < NE; ++e) cw[(size_t)t * NE + e] = cwl[e];
    zero_w[t] = zw;
    zw_s = zw;
  }
  __syncthreads();
  const float zw = zw_s;
  for (int i = l; i < HD; i += 64) out[(size_t)t * HD + i] = xs[i] * zw;
}

// ---------------- build per-expert token lists -----------------------------
__global__ void build_k(const float* __restrict__ cw, int* __restrict__ counts,
                        int* __restrict__ lists, float* __restrict__ wlist) {
  int t = blockIdx.x * blockDim.x + threadIdx.x;
  if (t >= T_TOK) return;
  for (int e = 0; e < NE; ++e) {
    float w = cw[(size_t)t * NE + e];
    if (w != 0.f) {
      int p = atomicAdd(&counts[e], 1);
      lists[e * T_TOK + p] = t;
      wlist[e * T_TOK + p] = w;
    }
  }
}

__global__ void scan_k(const int* __restrict__ counts, int* __restrict__ offs) {
  if (threadIdx.x == 0 && blockIdx.x == 0) {
    int s = 0;
    for (int e = 0; e < NE; ++e) { offs[e] = s; s += counts[e]; }
    offs[NE] = s;
  }
}

// ============================ gate/up GEMM =================================
// 256 thr / 4 waves (2M x 2N). Tile: 128M x 64N(g)+64N(u) x 64K.
// LDS: A [128][64] bf16 (pitch 128B, chunk^=(row&7)),
//      Bg/Bu [64][64] f32 (pitch 256B, chunk^=(row&15)), staged by
//      global_load_lds w/ inverse-swizzled per-lane global source.
__global__ __launch_bounds__(256) void gu_k(
    const unsigned short* __restrict__ xb,
    const float* __restrict__ wg, const float* __restrict__ wu,
    const int* __restrict__ counts, const int* __restrict__ offs,
    const int* __restrict__ lists, unsigned short* __restrict__ abuf) {
  const int e = blockIdx.z;
  const int cnt = counts[e];
  const int m0 = blockIdx.y * 128;
  if (m0 >= cnt) return;
  const int n0 = blockIdx.x * 64;

  __shared__ int toks[128];
  __shared__ char lA[16384];
  __shared__ char lG[16384];
  __shared__ char lU[16384];

  const int tid = threadIdx.x;
  if (tid < 128) {
    int m = m0 + tid;
    toks[tid] = (m < cnt) ? lists[e * T_TOK + m] : 0;
  }
  __syncthreads();

  // --- staging address precompute ---
  // A: 16B unit u = j*256+tid -> row = j*32 + (tid>>3), slot = tid&7
  const int arow = tid >> 3;                       // + j*32
  const int achunk = (tid & 7) ^ (arow & 7);       // inverse swizzle
  const unsigned short* asrc[4];
#pragma unroll
  for (int j = 0; j < 4; ++j)
    asrc[j] = xb + (size_t)toks[j * 32 + arow] * HD + achunk * 8;
  // B: unit u = j*256+tid -> row = j*16 + (tid>>4), slot = tid&15
  const int brow = tid >> 4;                       // + j*16
  const int bchunk = (tid & 15) ^ (brow & 15);
  const size_t wbase = (size_t)e * ID * HD;
  const float* gsrc[4]; const float* usrc[4];
#pragma unroll
  for (int j = 0; j < 4; ++j) {
    size_t ro = wbase + (size_t)(n0 + j * 16 + brow) * HD + bchunk * 4;
    gsrc[j] = wg + ro;
    usrc[j] = wu + ro;
  }
  char* const ldA = lA + tid * 16;
  char* const ldG = lG + tid * 16;
  char* const ldU = lU + tid * 16;

  const int wid = tid >> 6, l = tid & 63;
  const int wm = (wid >> 1) * 64, wn = (wid & 1) * 32;
  const int q = l >> 4, r = l & 15;

  f32x4 ag[4][2] = {}; f32x4 au[4][2] = {};

  for (int k0 = 0; k0 < HD; k0 += 64) {
#pragma unroll
    for (int j = 0; j < 4; ++j) {
      gload16(asrc[j] + k0, ldA + j * 4096);
      gload16(gsrc[j] + k0, ldG + j * 4096);
      gload16(usrc[j] + k0, ldU + j * 4096);
    }
    __syncthreads();   // compiler drains vmcnt before barrier
#pragma unroll
    for (int kk = 0; kk < 2; ++kk) {
      bf16x8 a[4];
#pragma unroll
      for (int fm = 0; fm < 4; ++fm) {
        int rr = wm + fm * 16 + r;
        a[fm] = *(const bf16x8*)(lA + rr * 128 + ((((kk << 2) + q) ^ (rr & 7)) << 4));
      }
#pragma unroll
      for (int fn = 0; fn < 2; ++fn) {
        int cc = wn + fn * 16 + r;
        int c0 = (kk << 3) + 2 * q;
        int sw = cc & 15;
        const char* pg = lG + cc * 256;
        const char* pu = lU + cc * 256;
        float4 g0 = *(const float4*)(pg + ((c0 ^ sw) << 4));
        float4 g1 = *(const float4*)(pg + (((c0 + 1) ^ sw) << 4));
        float4 u0 = *(const float4*)(pu + ((c0 ^ sw) << 4));
        float4 u1 = *(const float4*)(pu + (((c0 + 1) ^ sw) << 4));
        bf16x8 bg = cvt8(g0, g1), bu = cvt8(u0, u1);
#pragma unroll
        for (int fm = 0; fm < 4; ++fm) {
          ag[fm][fn] = MFMA(a[fm], bg, ag[fm][fn]);
          au[fm][fn] = MFMA(a[fm], bu, au[fm][fn]);
        }
      }
    }
    __syncthreads();   // protect LDS reuse
  }

  const int rowbase = offs[e] + m0;
#pragma unroll
  for (int fm = 0; fm < 4; ++fm)
#pragma unroll
    for (int fn = 0; fn < 2; ++fn)
#pragma unroll
      for (int i2 = 0; i2 < 4; ++i2) {
        int mr = wm + fm * 16 + q * 4 + i2;       // D: row=(l>>4)*4+reg
        if (m0 + mr < cnt) {
          float g = ag[fm][fn][i2], u = au[fm][fn][i2];
          float s = 1.0f / (1.0f + expf(-g));
          float aa = g * s * u;                   // silu(g)*u
          int col = n0 + wn + fn * 16 + r;        // D: col=l&15
          abuf[(size_t)(rowbase + mr) * ID + col] = f2bf(aa);
        }
      }
}

// ============================ down GEMM ====================================
// 256 thr / 4 waves (2M x 2N). Tile: 128M x 128N x 64K.
// LDS: A [128][64] bf16 (16KB), B [128][64] f32 (32KB).
__global__ __launch_bounds__(256) void dn_k(
    const unsigned short* __restrict__ abuf,
    const float* __restrict__ wd,
    const int* __restrict__ counts, const int* __restrict__ offs,
    const int* __restrict__ lists, const float* __restrict__ wlist,
    float* __restrict__ out) {
  const int e = blockIdx.z;
  const int cnt = counts[e];
  const int m0 = blockIdx.y * 128;
  if (m0 >= cnt) return;
  const int n0 = blockIdx.x * 128;

  __shared__ int toks[128];
  __shared__ float wts[128];
  __shared__ char lA[16384];
  __shared__ char lB[32768];

  const int tid = threadIdx.x;
  if (tid < 128) {
    int m = m0 + tid;
    if (m < cnt) { toks[tid] = lists[e * T_TOK + m]; wts[tid] = wlist[e * T_TOK + m]; }
    else         { toks[tid] = 0;                    wts[tid] = 0.f; }
  }
  __syncthreads();

  const int rowbase = offs[e] + m0;
  // A staging: row = j*32 + (tid>>3), slot = tid&7
  const int arow = tid >> 3;
  const int achunk = (tid & 7) ^ (arow & 7);
  const unsigned short* asrc[4];
#pragma unroll
  for (int j = 0; j < 4; ++j) {
    int row = j * 32 + arow;
    int grow = (m0 + row < cnt) ? rowbase + row : rowbase;   // clamp (pad rows)
    asrc[j] = abuf + (size_t)grow * ID + achunk * 8;
  }
  // B staging: row = j*16 + (tid>>4), slot = tid&15 (j = 0..7)
  const int brow = tid >> 4;
  const int bchunk = (tid & 15) ^ (brow & 15);
  const float* bsrc[8];
#pragma unroll
  for (int j = 0; j < 8; ++j)
    bsrc[j] = wd + (size_t)e * HD * ID + (size_t)(n0 + j * 16 + brow) * ID + bchunk * 4;
  char* const ldA = lA + tid * 16;
  char* const ldB = lB + tid * 16;

  const int wid = tid >> 6, l = tid & 63;
  const int wm = (wid >> 1) * 64, wn = (wid & 1) * 64;
  const int q = l >> 4, r = l & 15;

  f32x4 acc[4][4] = {};

  for (int k0 = 0; k0 < ID; k0 += 64) {
#pragma unroll
    for (int j = 0; j < 4; ++j) gload16(asrc[j] + k0, ldA + j * 4096);
#pragma unroll
    for (int j = 0; j < 8; ++j) gload16(bsrc[j] + k0, ldB + j * 4096);
    __syncthreads();
#pragma unroll
    for (int kk = 0; kk < 2; ++kk) {
      bf16x8 a[4];
#pragma unroll
      for (int fm = 0; fm < 4; ++fm) {
        int rr = wm + fm * 16 + r;
        a[fm] = *(const bf16x8*)(lA + rr * 128 + ((((kk << 2) + q) ^ (rr & 7)) << 4));
      }
#pragma unroll
      for (int fn = 0; fn < 4; ++fn) {
        int cc = wn + fn * 16 + r;
        int c0 = (kk << 3) + 2 * q;
        int sw = cc & 15;
        const char* pb = lB + cc * 256;
        float4 b0 = *(const float4*)(pb + ((c0 ^ sw) << 4));
        float4 b1 = *(const float4*)(pb + (((c0 + 1) ^ sw) << 4));
        bf16x8 b = cvt8(b0, b1);
#pragma unroll
        for (int fm = 0; fm < 4; ++fm)
          acc[fm][fn] = MFMA(a[fm], b, acc[fm][fn]);
      }
    }
    __syncthreads();
  }

#pragma unroll
  for (int fm = 0; fm < 4; ++fm)
#pragma unroll
    for (int fn = 0; fn < 4; ++fn)
#pragma unroll
      for (int i2 = 0; i2 < 4; ++i2) {
        int mr = wm + fm * 16 + q * 4 + i2;
        if (m0 + mr < cnt) {
          int col = n0 + wn + fn * 16 + r;
          atomicAdd(&out[(size_t)toks[mr] * HD + col], acc[fm][fn][i2] * wts[mr]);
        }
      }
}

extern "C" void kernel_launch(void* const* d_in, const int* in_sizes, int n_in,
                              void* d_out, int out_size, void* d_ws, size_t ws_size,
                              hipStream_t stream) {
  (void)in_sizes; (void)n_in; (void)out_size; (void)ws_size;
  const float* x    = (const float*)d_in[0];
  const float* wr   = (const float*)d_in[3];
  const float* bias = (const float*)d_in[4];
  const float* wg   = (const float*)d_in[5];
  const float* wu   = (const float*)d_in[6];
  const float* wd   = (const float*)d_in[7];
  float* out = (float*)d_out;

  char* p = (char*)d_ws;
  auto alloc = [&](size_t bytes) {
    char* r = p;
    p += (bytes + 255) & ~(size_t)255;
    return r;
  };
  float* cw      = (float*)alloc((size_t)T_TOK * NE * 4);
  float* zero_w  = (float*)alloc((size_t)T_TOK * 4);
  int*   counts  = (int*)alloc(NE * 4);
  int*   offs    = (int*)alloc((NE + 1) * 4);
  int*   lists   = (int*)alloc((size_t)NE * T_TOK * 4);
  float* wlist   = (float*)alloc((size_t)NE * T_TOK * 4);
  unsigned short* xb   = (unsigned short*)alloc((size_t)T_TOK * HD * 2);
  unsigned short* abuf = (unsigned short*)alloc((size_t)(T_TOK * NK + 128) * ID * 2);
  (void)zero_w;

  hipMemsetAsync(counts, 0, NE * 4, stream);
  router_k<<<T_TOK, 64, 0, stream>>>(x, wr, bias, cw, zero_w, xb, out);
  build_k<<<T_TOK / 256, 256, 0, stream>>>(cw, counts, lists, wlist);
  scan_k<<<1, 64, 0, stream>>>(counts, offs);
  gu_k<<<dim3(ID / 64, T_TOK / 128, NE), 256, 0, stream>>>(xb, wg, wu, counts, offs, lists, abuf);
  dn_k<<<dim3(HD / 128, T_TOK / 128, NE), 256, 0, stream>>>(abuf, wd, counts, offs, lists, wlist, out);
}